// Round 21
// baseline (218.946 us; speedup 1.0000x reference)
//
#include <hip/hip_runtime.h>

#define BB 32
#define TT 2048
#define CC 64
#define BT (BB * TT)
#define NCH 64
#define CL 32  // chunk length; NCH*CL == TT
#define GN_EPS (1e-5f * 64.f)
#define SW 36  // vT / k~T LDS stride
#define SA 68  // [t][i]-style LDS stride

typedef short short8 __attribute__((ext_vector_type(8)));
typedef float f32x4 __attribute__((ext_vector_type(4)));

// ---- helpers -------------------------------------------------------------
__device__ __forceinline__ float tanh_f(float x) {
  x = fminf(fmaxf(x, -10.f), 10.f);
  const float e = __expf(2.f * x);
  return (e - 1.f) / (e + 1.f);
}
__device__ __forceinline__ unsigned short f2bf(float x) {
  unsigned int u = __float_as_uint(x);
  u += 0x7FFFu + ((u >> 16) & 1u);   // RNE
  return (unsigned short)(u >> 16);
}
__device__ __forceinline__ float bf2f(unsigned short h) {
  return __uint_as_float(((unsigned int)h) << 16);
}
__device__ __forceinline__ short8 cvt8(const float4 a, const float4 b) {
  short8 h;
  h[0] = (short)f2bf(a.x); h[1] = (short)f2bf(a.y);
  h[2] = (short)f2bf(a.z); h[3] = (short)f2bf(a.w);
  h[4] = (short)f2bf(b.x); h[5] = (short)f2bf(b.y);
  h[6] = (short)f2bf(b.z); h[7] = (short)f2bf(b.w);
  return h;
}
__device__ __forceinline__ short8 lds8(const short* p) {
  return *reinterpret_cast<const short8*>(p);
}
__device__ __forceinline__ void splitload(const float* p, short8& h8, short8& l8) {
  const float4 v0 = *reinterpret_cast<const float4*>(p);
  const float4 v1 = *reinterpret_cast<const float4*>(p + 4);
  const float vv[8] = {v0.x, v0.y, v0.z, v0.w, v1.x, v1.y, v1.z, v1.w};
#pragma unroll
  for (int e = 0; e < 8; ++e) {
    const unsigned short hb = f2bf(vv[e]);
    h8[e] = (short)hb;
    l8[e] = (short)f2bf(vv[e] - bf2f(hb));
  }
}
__device__ __forceinline__ f32x4 mfma3(short8 ah, short8 al, short8 bh, short8 bl, f32x4 a) {
  a = __builtin_amdgcn_mfma_f32_16x16x32_bf16(ah, bh, a, 0, 0, 0);
  a = __builtin_amdgcn_mfma_f32_16x16x32_bf16(ah, bl, a, 0, 0, 0);
  a = __builtin_amdgcn_mfma_f32_16x16x32_bf16(al, bh, a, 0, 0, 0);
  return a;
}

// ---- preT: transpose + pre-convert ALL weights to bf16 (hi/lo for proj) --
__global__ __launch_bounds__(256) void preT_kernel(
    const float* __restrict__ maa_w1, const float* __restrict__ maa_w2,
    const float* __restrict__ dec_w1, const float* __restrict__ dec_w2,
    const float* __restrict__ Wr, const float* __restrict__ Wk,
    const float* __restrict__ Wv, const float* __restrict__ Wg,
    const float* __restrict__ Wo,
    short* __restrict__ w1Tb, short* __restrict__ w2Tb,
    short* __restrict__ d1Tb, short* __restrict__ d2Tb,
    short* __restrict__ Whi, short* __restrict__ Wlo)
{
  const int t0 = blockIdx.x * 256 + threadIdx.x;
  const int stride = gridDim.x * 256;
  for (int i = t0; i < 160 * 64; i += stride) {
    const int n = i >> 6, c = i & 63;
    w1Tb[i] = (short)f2bf(maa_w1[c * 160 + n]);
  }
  for (int i = t0; i < 5 * 64 * 32; i += stride) {
    const int f = i >> 11, rem = i & 2047, n = rem >> 5, q = rem & 31;
    w2Tb[i] = (short)f2bf(maa_w2[(f * 32 + q) * 64 + n]);
  }
  for (int i = t0; i < 4096; i += stride) {
    const int n = i >> 6, c = i & 63;
    d1Tb[i] = (short)f2bf(dec_w1[c * 64 + n]);
    d2Tb[i] = (short)f2bf(dec_w2[c * 64 + n]);
  }
  const float* Ws[5] = {Wr, Wk, Wv, Wg, Wo};
  for (int i = t0; i < 5 * 4096; i += stride) {
    const int q = i >> 12, idx = i & 4095;
    const float v = Ws[q][idx];
    const unsigned short hb = f2bf(v);
    Whi[i] = (short)hb;
    Wlo[i] = (short)f2bf(v - bf2f(hb));
  }
}

// ---- prep_fused: token-shift + mixing + decay + 4 projections + ct -------
// __launch_bounds__(256, 3): force VGPR <= ~170 for 3 waves/SIMD occupancy.
#define LDS_A 36
#define LDS_X 68
__global__ __launch_bounds__(256, 3) void prep_fused_kernel(
    const float* __restrict__ x,
    const float* __restrict__ tm_x, const float* __restrict__ tm_w, const float* __restrict__ tm_k,
    const float* __restrict__ tm_v, const float* __restrict__ tm_r, const float* __restrict__ tm_g,
    const short* __restrict__ w1Tb, const short* __restrict__ w2Tb,
    const short* __restrict__ d1Tb, const short* __restrict__ d2Tb,
    const float* __restrict__ t_decay, const float* __restrict__ u,
    const short* __restrict__ Whi, const short* __restrict__ Wlo,
    float* __restrict__ rkdc, float* __restrict__ v_o, float* __restrict__ g_o)
{
  __shared__ float aT[4][32][LDS_A];
  __shared__ float xT[4][32][LDS_X];
  const int lane = threadIdx.x & 63;
  const int wid = threadIdx.x >> 6;
  const int col = lane & 15, half = lane >> 4;
  const int tok0 = blockIdx.x * 128 + wid * 32;

  // A-layout xxx fragments
  short8 xa[2][2];
#pragma unroll
  for (int m = 0; m < 2; ++m)
#pragma unroll
    for (int kk = 0; kk < 2; ++kk) {
      const int tok = tok0 + m * 16 + col;
      const int kb = kk * 32 + half * 8;
      const float* pc = x + (size_t)tok * CC + kb;
      const float4 c0 = *reinterpret_cast<const float4*>(pc);
      const float4 c1 = *reinterpret_cast<const float4*>(pc + 4);
      float4 p0 = {0.f, 0.f, 0.f, 0.f}, p1 = {0.f, 0.f, 0.f, 0.f};
      if ((tok & (TT - 1)) != 0) {
        p0 = *reinterpret_cast<const float4*>(pc - CC);
        p1 = *reinterpret_cast<const float4*>(pc - CC + 4);
      }
      const float4 t0 = *reinterpret_cast<const float4*>(tm_x + kb);
      const float4 t1 = *reinterpret_cast<const float4*>(tm_x + kb + 4);
      const float cv[8] = {c0.x, c0.y, c0.z, c0.w, c1.x, c1.y, c1.z, c1.w};
      const float pv[8] = {p0.x, p0.y, p0.z, p0.w, p1.x, p1.y, p1.z, p1.w};
      const float tv[8] = {t0.x, t0.y, t0.z, t0.w, t1.x, t1.y, t1.z, t1.w};
      short8 h;
#pragma unroll
      for (int e = 0; e < 8; ++e)
        h[e] = (short)f2bf(fmaf(pv[e] - cv[e], tv[e], cv[e]));
      xa[m][kk] = h;
    }

  // C-layout xc/xx (held in registers — round-17-proven layout)
  float xcv[2][4][4], xxv[2][4][4];
#pragma unroll
  for (int m = 0; m < 2; ++m)
#pragma unroll
    for (int reg = 0; reg < 4; ++reg) {
      const int tok = tok0 + m * 16 + half * 4 + reg;
      const bool has = (tok & (TT - 1)) != 0;
#pragma unroll
      for (int nt = 0; nt < 4; ++nt) {
        const size_t o = (size_t)tok * CC + nt * 16 + col;
        const float cur = x[o];
        const float prv = has ? x[o - CC] : 0.f;
        xcv[m][nt][reg] = cur;
        xxv[m][nt][reg] = prv - cur;
      }
    }

  // mixing pipeline: produce xf in C-layout, store to wave LDS xT[t][c]
  auto mix_f = [&](int f, const float* __restrict__ tmf) {
    f32x4 acc1[2][2];
#pragma unroll
    for (int m = 0; m < 2; ++m)
#pragma unroll
      for (int ntf = 0; ntf < 2; ++ntf) acc1[m][ntf] = (f32x4){0.f, 0.f, 0.f, 0.f};
#pragma unroll
    for (int ntf = 0; ntf < 2; ++ntf)
#pragma unroll
      for (int kk = 0; kk < 2; ++kk) {
        const short8 b1 = lds8(w1Tb + (size_t)(f * 32 + ntf * 16 + col) * 64 + kk * 32 + half * 8);
#pragma unroll
        for (int m = 0; m < 2; ++m)
          acc1[m][ntf] = __builtin_amdgcn_mfma_f32_16x16x32_bf16(
              xa[m][kk], b1, acc1[m][ntf], 0, 0, 0);
      }
#pragma unroll
    for (int m = 0; m < 2; ++m)
#pragma unroll
      for (int ntf = 0; ntf < 2; ++ntf)
#pragma unroll
        for (int reg = 0; reg < 4; ++reg)
          aT[wid][m * 16 + half * 4 + reg][ntf * 16 + col] = tanh_f(acc1[m][ntf][reg]);
    short8 a2[2];
#pragma unroll
    for (int m = 0; m < 2; ++m) {
      const float4 v0 = *reinterpret_cast<const float4*>(&aT[wid][m * 16 + col][half * 8]);
      const float4 v1 = *reinterpret_cast<const float4*>(&aT[wid][m * 16 + col][half * 8 + 4]);
      a2[m] = cvt8(v0, v1);
    }
    f32x4 acc2[2][4];
#pragma unroll
    for (int m = 0; m < 2; ++m)
#pragma unroll
      for (int nt = 0; nt < 4; ++nt) acc2[m][nt] = (f32x4){0.f, 0.f, 0.f, 0.f};
#pragma unroll
    for (int nt = 0; nt < 4; ++nt) {
      const short8 b2 = lds8(w2Tb + (size_t)f * 2048 + (nt * 16 + col) * 32 + half * 8);
#pragma unroll
      for (int m = 0; m < 2; ++m)
        acc2[m][nt] = __builtin_amdgcn_mfma_f32_16x16x32_bf16(
            a2[m], b2, acc2[m][nt], 0, 0, 0);
    }
    float tmf4[4];
#pragma unroll
    for (int nt = 0; nt < 4; ++nt) tmf4[nt] = tmf[nt * 16 + col];
#pragma unroll
    for (int m = 0; m < 2; ++m)
#pragma unroll
      for (int nt = 0; nt < 4; ++nt)
#pragma unroll
        for (int reg = 0; reg < 4; ++reg)
          xT[wid][m * 16 + half * 4 + reg][nt * 16 + col] =
              fmaf(xxv[m][nt][reg], tmf4[nt] + acc2[m][nt][reg], xcv[m][nt][reg]);
  };
  // A-layout 3-product fragments of the stream currently in xT
  auto xT_afrag = [&](short8 ah[2][2], short8 al[2][2]) {
#pragma unroll
    for (int m = 0; m < 2; ++m)
#pragma unroll
      for (int kk = 0; kk < 2; ++kk)
        splitload(&xT[wid][m * 16 + col][kk * 32 + half * 8], ah[m][kk], al[m][kk]);
  };
  // proj GEMM vs pre-converted hi/lo weights (linear [out][in] layout)
  auto proj_gemm = [&](const short* __restrict__ Wh, const short* __restrict__ Wl,
                       const short8 ah[2][2], const short8 al[2][2], f32x4 acc[2][4]) {
#pragma unroll
    for (int m = 0; m < 2; ++m)
#pragma unroll
      for (int n = 0; n < 4; ++n) acc[m][n] = (f32x4){0.f, 0.f, 0.f, 0.f};
#pragma unroll
    for (int n = 0; n < 4; ++n)
#pragma unroll
      for (int kk = 0; kk < 2; ++kk) {
        const short8 bh = lds8(Wh + (size_t)(n * 16 + col) * CC + kk * 32 + half * 8);
        const short8 bl = lds8(Wl + (size_t)(n * 16 + col) * CC + kk * 32 + half * 8);
#pragma unroll
        for (int m = 0; m < 2; ++m)
          acc[m][n] = mfma3(ah[m][kk], al[m][kk], bh, bl, acc[m][n]);
      }
  };

  short8 ah[2][2], al[2][2];

  // ---- phase W: xw -> decay MLP -> ew (held in regs) ----
  mix_f(0, tm_w);
  short8 xwh[2][2];
#pragma unroll
  for (int m = 0; m < 2; ++m)
#pragma unroll
    for (int kk = 0; kk < 2; ++kk) {
      const float4 v0 = *reinterpret_cast<const float4*>(&xT[wid][m * 16 + col][kk * 32 + half * 8]);
      const float4 v1 = *reinterpret_cast<const float4*>(&xT[wid][m * 16 + col][kk * 32 + half * 8 + 4]);
      xwh[m][kk] = cvt8(v0, v1);
    }
  f32x4 hcc[2][4];
#pragma unroll
  for (int m = 0; m < 2; ++m)
#pragma unroll
    for (int nt = 0; nt < 4; ++nt) hcc[m][nt] = (f32x4){0.f, 0.f, 0.f, 0.f};
#pragma unroll
  for (int nt = 0; nt < 4; ++nt)
#pragma unroll
    for (int kk = 0; kk < 2; ++kk) {
      const short8 bd = lds8(d1Tb + (size_t)(nt * 16 + col) * 64 + kk * 32 + half * 8);
#pragma unroll
      for (int m = 0; m < 2; ++m)
        hcc[m][nt] = __builtin_amdgcn_mfma_f32_16x16x32_bf16(
            xwh[m][kk], bd, hcc[m][nt], 0, 0, 0);
    }
#pragma unroll
  for (int m = 0; m < 2; ++m)
#pragma unroll
    for (int nt = 0; nt < 4; ++nt)
#pragma unroll
      for (int reg = 0; reg < 4; ++reg)
        xT[wid][m * 16 + half * 4 + reg][nt * 16 + col] = tanh_f(hcc[m][nt][reg]);
#pragma unroll
  for (int m = 0; m < 2; ++m)
#pragma unroll
    for (int kk = 0; kk < 2; ++kk) {
      const float4 v0 = *reinterpret_cast<const float4*>(&xT[wid][m * 16 + col][kk * 32 + half * 8]);
      const float4 v1 = *reinterpret_cast<const float4*>(&xT[wid][m * 16 + col][kk * 32 + half * 8 + 4]);
      xwh[m][kk] = cvt8(v0, v1);
    }
  f32x4 wfa[2][4];
#pragma unroll
  for (int m = 0; m < 2; ++m)
#pragma unroll
    for (int nt = 0; nt < 4; ++nt) wfa[m][nt] = (f32x4){0.f, 0.f, 0.f, 0.f};
#pragma unroll
  for (int nt = 0; nt < 4; ++nt)
#pragma unroll
    for (int kk = 0; kk < 2; ++kk) {
      const short8 bd = lds8(d2Tb + (size_t)(nt * 16 + col) * 64 + kk * 32 + half * 8);
#pragma unroll
      for (int m = 0; m < 2; ++m)
        wfa[m][nt] = __builtin_amdgcn_mfma_f32_16x16x32_bf16(
            xwh[m][kk], bd, wfa[m][nt], 0, 0, 0);
    }
  float ewv[2][4][4];
  {
    float td4[4];
#pragma unroll
    for (int nt = 0; nt < 4; ++nt) td4[nt] = t_decay[nt * 16 + col];
#pragma unroll
    for (int m = 0; m < 2; ++m)
#pragma unroll
      for (int nt = 0; nt < 4; ++nt)
#pragma unroll
        for (int reg = 0; reg < 4; ++reg)
          ewv[m][nt][reg] = __expf(wfa[m][nt][reg] + td4[nt]);
  }

  // ---- phase R ----
  mix_f(3, tm_r);
  xT_afrag(ah, al);
  f32x4 accr[2][4];
  proj_gemm(Whi, Wlo, ah, al, accr);                    // Wr

  // ---- phase K + ct + full rkdc write ----
  mix_f(1, tm_k);
  xT_afrag(ah, al);
  f32x4 acck[2][4];
  proj_gemm(Whi + 4096, Wlo + 4096, ah, al, acck);      // Wk

  float uv[4];
#pragma unroll
  for (int n = 0; n < 4; ++n) uv[n] = u[n * 16 + col];
#pragma unroll
  for (int m = 0; m < 2; ++m) {
    float ctv[4];
#pragma unroll
    for (int reg = 0; reg < 4; ++reg) {
      float p = 0.f;
#pragma unroll
      for (int n = 0; n < 4; ++n)
        p += accr[m][n][reg] * uv[n] * acck[m][n][reg];
      p += __shfl_xor(p, 1, 64);
      p += __shfl_xor(p, 2, 64);
      p += __shfl_xor(p, 4, 64);
      p += __shfl_xor(p, 8, 64);
      ctv[reg] = p;
    }
#pragma unroll
    for (int n = 0; n < 4; ++n)
#pragma unroll
      for (int reg = 0; reg < 4; ++reg) {
        const int token = tok0 + m * 16 + half * 4 + reg;
        const size_t o = (size_t)token * CC + n * 16 + col;
        *reinterpret_cast<float4*>(rkdc + 4 * o) =
            make_float4(accr[m][n][reg], acck[m][n][reg], ewv[m][n][reg], ctv[reg]);
      }
  }

  // ---- phase V ----
  mix_f(2, tm_v);
  xT_afrag(ah, al);
  proj_gemm(Whi + 2 * 4096, Wlo + 2 * 4096, ah, al, accr);  // Wv
#pragma unroll
  for (int m = 0; m < 2; ++m)
#pragma unroll
    for (int n = 0; n < 4; ++n)
#pragma unroll
      for (int reg = 0; reg < 4; ++reg) {
        const int token = tok0 + m * 16 + half * 4 + reg;
        v_o[(size_t)token * CC + n * 16 + col] = accr[m][n][reg];
      }

  // ---- phase G ----
  mix_f(4, tm_g);
  xT_afrag(ah, al);
  proj_gemm(Whi + 3 * 4096, Wlo + 3 * 4096, ah, al, accr);  // Wg
#pragma unroll
  for (int m = 0; m < 2; ++m)
#pragma unroll
    for (int n = 0; n < 4; ++n)
#pragma unroll
      for (int reg = 0; reg < 4; ++reg) {
        const int token = tok0 + m * 16 + half * 4 + reg;
        const float gg = accr[m][n][reg];
        g_o[(size_t)token * CC + n * 16 + col] = gg / (1.f + __expf(-gg));
      }
}

// ---- A (MFMA): S^T[j][i] = exp(-cumEnd[i]) * sum_s v[s][j] k~[s][i] ------
__global__ __launch_bounds__(128) void chunkA_mfma_kernel(
    const float4* __restrict__ rkdc, const float* __restrict__ v_i,
    float* __restrict__ SlocT, float* __restrict__ Dp)
{
  __shared__ float ktS[2][64 * SW];
  __shared__ float vtS[2][64 * SW];
  __shared__ float cumS[2][64];
  const int lane = threadIdx.x & 63;
  const int w = threadIdx.x >> 6;
  const int bch = __builtin_amdgcn_readfirstlane((blockIdx.x << 1) + w);
  float* ktL = ktS[w];
  float* vtL = vtS[w];
  float* cumL = cumS[w];
  const int col = lane & 15, half = lane >> 4;

  const float4* fq = rkdc + (size_t)bch * (CL * CC) + lane;
  const float* vq = v_i + (size_t)bch * (CL * CC) + lane;

  float cum = 0.f;
  for (int t = 0; t < CL; ++t) {
    const float4 f = fq[t * CC];
    const float vv = vq[t * CC];
    cum += f.z;
    ktL[lane * SW + t] = f.y * __expf(cum);
    vtL[lane * SW + t] = vv;
  }
  cumL[lane] = cum;
  Dp[(size_t)bch * CC + lane] = __expf(-cum);

  short8 vah[4], val[4], kbh[4], kbl[4];
#pragma unroll
  for (int m = 0; m < 4; ++m)
    splitload(vtL + (m * 16 + col) * SW + half * 8, vah[m], val[m]);
#pragma unroll
  for (int n = 0; n < 4; ++n)
    splitload(ktL + (n * 16 + col) * SW + half * 8, kbh[n], kbl[n]);

  f32x4 acc[4][4];
#pragma unroll
  for (int m = 0; m < 4; ++m)
#pragma unroll
    for (int n = 0; n < 4; ++n) {
      acc[m][n] = (f32x4){0.f, 0.f, 0.f, 0.f};
      acc[m][n] = mfma3(vah[m], val[m], kbh[n], kbl[n], acc[m][n]);
    }

  float acl[4];
#pragma unroll
  for (int n = 0; n < 4; ++n) acl[n] = __expf(-cumL[n * 16 + col]);

  float* so = SlocT + (size_t)bch * (CC * CC);
#pragma unroll
  for (int m = 0; m < 4; ++m)
#pragma unroll
    for (int n = 0; n < 4; ++n)
#pragma unroll
      for (int reg = 0; reg < 4; ++reg) {
        const int jj = m * 16 + half * 4 + reg;
        const int ii = n * 16 + col;
        so[jj * CC + ii] = acc[m][n][reg] * acl[n];
      }
}

// ---- B: in-place combine over chunks (transposed [j][i] layout) ----------
__global__ __launch_bounds__(1024) void combine_kernel(
    float* __restrict__ buf, const float* __restrict__ Dp)
{
  const int b = blockIdx.x, tid = threadIdx.x;
  __shared__ float sDp[NCH * CC];
  for (int idx = tid; idx < NCH * CC; idx += 1024)
    sDp[idx] = Dp[(size_t)b * NCH * CC + idx];
  __syncthreads();
  float run[4] = {0.f, 0.f, 0.f, 0.f};
  for (int ch = 0; ch < NCH; ++ch) {
    const size_t base = ((size_t)(b * NCH + ch)) * (CC * CC);
    const float* drow = sDp + ch * CC;
#pragma unroll
    for (int k2 = 0; k2 < 4; ++k2) {
      const int idx = tid + (k2 << 10);
      const float tmp = buf[base + idx];
      buf[base + idx] = run[k2];
      run[k2] = fmaf(run[k2], drow[idx & 63], tmp);
    }
  }
}

// ---- C (MFMA): y = mask(R~K~^T, diag<-ct)@V + R~@S0; GN; *g; @Wo^T -------
__global__ __launch_bounds__(128) void scanC_mfma_kernel(
    const float4* __restrict__ rkdc, const float* __restrict__ v_i,
    const float* __restrict__ S0T, const float* __restrict__ g_i,
    const float* __restrict__ ln_w, const float* __restrict__ ln_b,
    const short* __restrict__ Wohi, const short* __restrict__ Wolo,
    float* __restrict__ out)
{
  __shared__ float rtS[2][32 * SA];
  __shared__ float ktS[2][32 * SA];
  __shared__ float vtS[2][64 * SW];
  __shared__ float ctS[2][CL];
  const int lane = threadIdx.x & 63;
  const int w = threadIdx.x >> 6;
  const int bch = __builtin_amdgcn_readfirstlane((blockIdx.x << 1) + w);
  float* rtL = rtS[w];
  float* ktL = ktS[w];
  float* vtL = vtS[w];
  float* ctL = ctS[w];
  const int col = lane & 15, half = lane >> 4;

  const float4* fq = rkdc + (size_t)bch * (CL * CC) + lane;
  const float* vq = v_i + (size_t)bch * (CL * CC) + lane;

  float cum = 0.f;
  for (int t = 0; t < CL; ++t) {
    const float4 f = fq[t * CC];
    const float vv = vq[t * CC];
    rtL[t * SA + lane] = f.x * __expf(-cum);
    cum += f.z;
    ktL[t * SA + lane] = f.y * __expf(cum);
    vtL[lane * SW + t] = vv;
    if (lane == 0) ctL[t] = f.w;
  }

  short8 rah[2][2], ral[2][2];
#pragma unroll
  for (int m = 0; m < 2; ++m)
#pragma unroll
    for (int kk = 0; kk < 2; ++kk)
      splitload(rtL + (m * 16 + col) * SA + kk * 32 + half * 8, rah[m][kk], ral[m][kk]);
  short8 kbh[2][2], kbl[2][2];
#pragma unroll
  for (int n = 0; n < 2; ++n)
#pragma unroll
    for (int kk = 0; kk < 2; ++kk)
      splitload(ktL + (n * 16 + col) * SA + kk * 32 + half * 8, kbh[n][kk], kbl[n][kk]);

  f32x4 pacc[2][2];
#pragma unroll
  for (int m = 0; m < 2; ++m)
#pragma unroll
    for (int n = 0; n < 2; ++n) {
      pacc[m][n] = (f32x4){0.f, 0.f, 0.f, 0.f};
#pragma unroll
      for (int kk = 0; kk < 2; ++kk)
        pacc[m][n] = mfma3(rah[m][kk], ral[m][kk], kbh[n][kk], kbl[n][kk], pacc[m][n]);
    }

#pragma unroll
  for (int m = 0; m < 2; ++m)
#pragma unroll
    for (int n = 0; n < 2; ++n)
#pragma unroll
      for (int reg = 0; reg < 4; ++reg) {
        const int tt = m * 16 + half * 4 + reg;
        const int ss = n * 16 + col;
        const float pv = (ss < tt) ? pacc[m][n][reg] : (ss == tt ? ctL[tt] : 0.f);
        ktL[tt * SA + ss] = pv;
      }

  short8 pah[2], pal[2];
#pragma unroll
  for (int m = 0; m < 2; ++m)
    splitload(ktL + (m * 16 + col) * SA + half * 8, pah[m], pal[m]);
  short8 vbh[4], vbl[4];
#pragma unroll
  for (int n = 0; n < 4; ++n)
    splitload(vtL + (n * 16 + col) * SW + half * 8, vbh[n], vbl[n]);

  f32x4 yacc[2][4];
#pragma unroll
  for (int m = 0; m < 2; ++m)
#pragma unroll
    for (int n = 0; n < 4; ++n) {
      yacc[m][n] = (f32x4){0.f, 0.f, 0.f, 0.f};
      yacc[m][n] = mfma3(pah[m], pal[m], vbh[n], vbl[n], yacc[m][n]);
    }

  const float* s0b = S0T + (size_t)bch * (CC * CC);
#pragma unroll
  for (int kk = 0; kk < 2; ++kk) {
    short8 sbh[4], sbl[4];
#pragma unroll
    for (int n = 0; n < 4; ++n)
      splitload(s0b + (size_t)(n * 16 + col) * CC + kk * 32 + half * 8, sbh[n], sbl[n]);
#pragma unroll
    for (int m = 0; m < 2; ++m)
#pragma unroll
      for (int n = 0; n < 4; ++n)
        yacc[m][n] = mfma3(rah[m][kk], ral[m][kk], sbh[n], sbl[n], yacc[m][n]);
  }

  float s1v[2][4], s2v[2][4];
#pragma unroll
  for (int m = 0; m < 2; ++m)
#pragma unroll
    for (int reg = 0; reg < 4; ++reg) {
      float a = 0.f, b2 = 0.f;
#pragma unroll
      for (int n = 0; n < 4; ++n) {
        const float y = yacc[m][n][reg];
        a += y; b2 += y * y;
      }
      a += __shfl_xor(a, 1, 64); b2 += __shfl_xor(b2, 1, 64);
      a += __shfl_xor(a, 2, 64); b2 += __shfl_xor(b2, 2, 64);
      a += __shfl_xor(a, 4, 64); b2 += __shfl_xor(b2, 4, 64);
      a += __shfl_xor(a, 8, 64); b2 += __shfl_xor(b2, 8, 64);
      s1v[m][reg] = a; s2v[m][reg] = b2;
    }

#pragma unroll
  for (int m = 0; m < 2; ++m)
#pragma unroll
    for (int n = 0; n < 4; ++n) {
      const int cj = n * 16 + col;
      const float lnw = ln_w[cj], lnb = ln_b[cj];
#pragma unroll
      for (int reg = 0; reg < 4; ++reg) {
        const int tt = m * 16 + half * 4 + reg;
        const float y = yacc[m][n][reg];
        const float mu = s1v[m][reg] * (1.f / CC);
        const float var = s2v[m][reg] * (1.f / CC) - mu * mu;
        const float z = (y - mu) * rsqrtf(var + GN_EPS) * lnw + lnb;
        const float gg = g_i[((size_t)bch * CL + tt) * CC + cj];
        rtL[tt * SA + cj] = z * gg;
      }
    }

  f32x4 oacc[2][4];
#pragma unroll
  for (int m = 0; m < 2; ++m)
#pragma unroll
    for (int n = 0; n < 4; ++n) oacc[m][n] = (f32x4){0.f, 0.f, 0.f, 0.f};
#pragma unroll
  for (int kk = 0; kk < 2; ++kk) {
    short8 zah[2], zal[2];
#pragma unroll
    for (int m = 0; m < 2; ++m)
      splitload(rtL + (m * 16 + col) * SA + kk * 32 + half * 8, zah[m], zal[m]);
#pragma unroll
    for (int n = 0; n < 4; ++n) {
      const short8 wbh = lds8(Wohi + (size_t)(n * 16 + col) * CC + kk * 32 + half * 8);
      const short8 wbl = lds8(Wolo + (size_t)(n * 16 + col) * CC + kk * 32 + half * 8);
#pragma unroll
      for (int m = 0; m < 2; ++m)
        oacc[m][n] = mfma3(zah[m], zal[m], wbh, wbl, oacc[m][n]);
    }
  }

#pragma unroll
  for (int m = 0; m < 2; ++m)
#pragma unroll
    for (int n = 0; n < 4; ++n)
#pragma unroll
      for (int reg = 0; reg < 4; ++reg) {
        const int tt = m * 16 + half * 4 + reg;
        out[((size_t)bch * CL + tt) * CC + n * 16 + col] = oacc[m][n][reg];
      }
}

extern "C" void kernel_launch(void* const* d_in, const int* in_sizes, int n_in,
                              void* d_out, int out_size, void* d_ws, size_t ws_size,
                              hipStream_t stream) {
  const float* x       = (const float*)d_in[0];
  const float* tm_x    = (const float*)d_in[1];
  const float* tm_w    = (const float*)d_in[2];
  const float* tm_k    = (const float*)d_in[3];
  const float* tm_v    = (const float*)d_in[4];
  const float* tm_r    = (const float*)d_in[5];
  const float* tm_g    = (const float*)d_in[6];
  const float* maa_w1  = (const float*)d_in[7];
  const float* maa_w2  = (const float*)d_in[8];
  const float* t_decay = (const float*)d_in[9];
  const float* dec_w1  = (const float*)d_in[10];
  const float* dec_w2  = (const float*)d_in[11];
  const float* u       = (const float*)d_in[12];
  const float* Wr      = (const float*)d_in[13];
  const float* Wk      = (const float*)d_in[14];
  const float* Wv      = (const float*)d_in[15];
  const float* Wg      = (const float*)d_in[16];
  const float* Wo      = (const float*)d_in[17];
  const float* ln_w    = (const float*)d_in[18];
  const float* ln_b    = (const float*)d_in[19];

  const size_t M = (size_t)BT * CC;  // 4.19M floats
  float* ws   = (float*)d_ws;
  float* scb  = ws;                  // SlocT==S0T (in-place), 2M floats
  float* Dp   = ws + 2 * M;
  float* g_o  = ws + 4 * M;
  float* v_o  = ws + 5 * M;
  float* rkdc = ws + 6 * M;
  short* w1Tb = (short*)(ws + 10 * M);
  short* w2Tb = w1Tb + 10240;
  short* d1Tb = w2Tb + 10240;
  short* d2Tb = d1Tb + 4096;
  short* Whi  = d2Tb + 4096;
  short* Wlo  = Whi + 5 * 4096;
  float* out  = (float*)d_out;

  preT_kernel<<<64, 256, 0, stream>>>(
      maa_w1, maa_w2, dec_w1, dec_w2, Wr, Wk, Wv, Wg, Wo,
      w1Tb, w2Tb, d1Tb, d2Tb, Whi, Wlo);

  prep_fused_kernel<<<BT / 128, 256, 0, stream>>>(
      x, tm_x, tm_w, tm_k, tm_v, tm_r, tm_g,
      w1Tb, w2Tb, d1Tb, d2Tb, t_decay, u,
      Whi, Wlo, rkdc, v_o, g_o);

  chunkA_mfma_kernel<<<(BB * NCH) / 2, 128, 0, stream>>>(
      (const float4*)rkdc, v_o, scb, Dp);

  combine_kernel<<<BB, 1024, 0, stream>>>(scb, Dp);

  scanC_mfma_kernel<<<(BB * NCH) / 2, 128, 0, stream>>>(
      (const float4*)rkdc, v_o, scb, g_o, ln_w, ln_b,
      Whi + 4 * 4096, Wlo + 4 * 4096, out);
}

// Round 22
// 159.060 us; speedup vs baseline: 1.3765x; 1.3765x over previous
//
#include <hip/hip_runtime.h>

#define BB 32
#define TT 2048
#define CC 64
#define BT (BB * TT)
#define NCH 64
#define CL 32  // chunk length; NCH*CL == TT
#define GN_EPS (1e-5f * 64.f)
#define SW 36  // vT / k~T LDS stride
#define SA 68  // [t][i]-style LDS stride

typedef short short8 __attribute__((ext_vector_type(8)));
typedef float f32x4 __attribute__((ext_vector_type(4)));

// ---- helpers -------------------------------------------------------------
__device__ __forceinline__ float tanh_f(float x) {
  x = fminf(fmaxf(x, -10.f), 10.f);
  const float e = __expf(2.f * x);
  return (e - 1.f) / (e + 1.f);
}
__device__ __forceinline__ unsigned short f2bf(float x) {
  unsigned int u = __float_as_uint(x);
  u += 0x7FFFu + ((u >> 16) & 1u);   // RNE
  return (unsigned short)(u >> 16);
}
__device__ __forceinline__ float bf2f(unsigned short h) {
  return __uint_as_float(((unsigned int)h) << 16);
}
__device__ __forceinline__ short8 cvt8(const float4 a, const float4 b) {
  short8 h;
  h[0] = (short)f2bf(a.x); h[1] = (short)f2bf(a.y);
  h[2] = (short)f2bf(a.z); h[3] = (short)f2bf(a.w);
  h[4] = (short)f2bf(b.x); h[5] = (short)f2bf(b.y);
  h[6] = (short)f2bf(b.z); h[7] = (short)f2bf(b.w);
  return h;
}
__device__ __forceinline__ short8 lds8(const short* p) {
  return *reinterpret_cast<const short8*>(p);
}
__device__ __forceinline__ void splitload(const float* p, short8& h8, short8& l8) {
  const float4 v0 = *reinterpret_cast<const float4*>(p);
  const float4 v1 = *reinterpret_cast<const float4*>(p + 4);
  const float vv[8] = {v0.x, v0.y, v0.z, v0.w, v1.x, v1.y, v1.z, v1.w};
#pragma unroll
  for (int e = 0; e < 8; ++e) {
    const unsigned short hb = f2bf(vv[e]);
    h8[e] = (short)hb;
    l8[e] = (short)f2bf(vv[e] - bf2f(hb));
  }
}
__device__ __forceinline__ f32x4 mfma3(short8 ah, short8 al, short8 bh, short8 bl, f32x4 a) {
  a = __builtin_amdgcn_mfma_f32_16x16x32_bf16(ah, bh, a, 0, 0, 0);
  a = __builtin_amdgcn_mfma_f32_16x16x32_bf16(ah, bl, a, 0, 0, 0);
  a = __builtin_amdgcn_mfma_f32_16x16x32_bf16(al, bh, a, 0, 0, 0);
  return a;
}

// ---- preT: transpose + pre-convert ALL weights to bf16 (hi/lo for proj) --
__global__ __launch_bounds__(256) void preT_kernel(
    const float* __restrict__ maa_w1, const float* __restrict__ maa_w2,
    const float* __restrict__ dec_w1, const float* __restrict__ dec_w2,
    const float* __restrict__ Wr, const float* __restrict__ Wk,
    const float* __restrict__ Wv, const float* __restrict__ Wg,
    const float* __restrict__ Wo,
    short* __restrict__ w1Tb, short* __restrict__ w2Tb,
    short* __restrict__ d1Tb, short* __restrict__ d2Tb,
    short* __restrict__ Whi, short* __restrict__ Wlo)
{
  const int t0 = blockIdx.x * 256 + threadIdx.x;
  const int stride = gridDim.x * 256;
  for (int i = t0; i < 160 * 64; i += stride) {
    const int n = i >> 6, c = i & 63;
    w1Tb[i] = (short)f2bf(maa_w1[c * 160 + n]);
  }
  for (int i = t0; i < 5 * 64 * 32; i += stride) {
    const int f = i >> 11, rem = i & 2047, n = rem >> 5, q = rem & 31;
    w2Tb[i] = (short)f2bf(maa_w2[(f * 32 + q) * 64 + n]);
  }
  for (int i = t0; i < 4096; i += stride) {
    const int n = i >> 6, c = i & 63;
    d1Tb[i] = (short)f2bf(dec_w1[c * 64 + n]);
    d2Tb[i] = (short)f2bf(dec_w2[c * 64 + n]);
  }
  const float* Ws[5] = {Wr, Wk, Wv, Wg, Wo};
  for (int i = t0; i < 5 * 4096; i += stride) {
    const int q = i >> 12, idx = i & 4095;
    const float v = Ws[q][idx];
    const unsigned short hb = f2bf(v);
    Whi[i] = (short)hb;
    Wlo[i] = (short)f2bf(v - bf2f(hb));
  }
}

// ---- prep_fused: token-shift + mixing + decay + 4 projections + ct -------
#define LDS_A 36
#define LDS_X 68
__global__ __launch_bounds__(256) void prep_fused_kernel(
    const float* __restrict__ x,
    const float* __restrict__ tm_x, const float* __restrict__ tm_w, const float* __restrict__ tm_k,
    const float* __restrict__ tm_v, const float* __restrict__ tm_r, const float* __restrict__ tm_g,
    const short* __restrict__ w1Tb, const short* __restrict__ w2Tb,
    const short* __restrict__ d1Tb, const short* __restrict__ d2Tb,
    const float* __restrict__ t_decay, const float* __restrict__ u,
    const short* __restrict__ Whi, const short* __restrict__ Wlo,
    float* __restrict__ rkdc, float* __restrict__ v_o, float* __restrict__ g_o)
{
  __shared__ float aT[4][32][LDS_A];
  __shared__ float xT[4][32][LDS_X];
  const int lane = threadIdx.x & 63;
  const int wid = threadIdx.x >> 6;
  const int col = lane & 15, half = lane >> 4;
  const int tok0 = blockIdx.x * 128 + wid * 32;

  // A-layout xxx fragments
  short8 xa[2][2];
#pragma unroll
  for (int m = 0; m < 2; ++m)
#pragma unroll
    for (int kk = 0; kk < 2; ++kk) {
      const int tok = tok0 + m * 16 + col;
      const int kb = kk * 32 + half * 8;
      const float* pc = x + (size_t)tok * CC + kb;
      const float4 c0 = *reinterpret_cast<const float4*>(pc);
      const float4 c1 = *reinterpret_cast<const float4*>(pc + 4);
      float4 p0 = {0.f, 0.f, 0.f, 0.f}, p1 = {0.f, 0.f, 0.f, 0.f};
      if ((tok & (TT - 1)) != 0) {
        p0 = *reinterpret_cast<const float4*>(pc - CC);
        p1 = *reinterpret_cast<const float4*>(pc - CC + 4);
      }
      const float4 t0 = *reinterpret_cast<const float4*>(tm_x + kb);
      const float4 t1 = *reinterpret_cast<const float4*>(tm_x + kb + 4);
      const float cv[8] = {c0.x, c0.y, c0.z, c0.w, c1.x, c1.y, c1.z, c1.w};
      const float pv[8] = {p0.x, p0.y, p0.z, p0.w, p1.x, p1.y, p1.z, p1.w};
      const float tv[8] = {t0.x, t0.y, t0.z, t0.w, t1.x, t1.y, t1.z, t1.w};
      short8 h;
#pragma unroll
      for (int e = 0; e < 8; ++e)
        h[e] = (short)f2bf(fmaf(pv[e] - cv[e], tv[e], cv[e]));
      xa[m][kk] = h;
    }

  // C-layout xc/xx (held in registers — round-17-proven layout)
  float xcv[2][4][4], xxv[2][4][4];
#pragma unroll
  for (int m = 0; m < 2; ++m)
#pragma unroll
    for (int reg = 0; reg < 4; ++reg) {
      const int tok = tok0 + m * 16 + half * 4 + reg;
      const bool has = (tok & (TT - 1)) != 0;
#pragma unroll
      for (int nt = 0; nt < 4; ++nt) {
        const size_t o = (size_t)tok * CC + nt * 16 + col;
        const float cur = x[o];
        const float prv = has ? x[o - CC] : 0.f;
        xcv[m][nt][reg] = cur;
        xxv[m][nt][reg] = prv - cur;
      }
    }

  // mixing pipeline: produce xf in C-layout, store to wave LDS xT[t][c]
  auto mix_f = [&](int f, const float* __restrict__ tmf) {
    f32x4 acc1[2][2];
#pragma unroll
    for (int m = 0; m < 2; ++m)
#pragma unroll
      for (int ntf = 0; ntf < 2; ++ntf) acc1[m][ntf] = (f32x4){0.f, 0.f, 0.f, 0.f};
#pragma unroll
    for (int ntf = 0; ntf < 2; ++ntf)
#pragma unroll
      for (int kk = 0; kk < 2; ++kk) {
        const short8 b1 = lds8(w1Tb + (size_t)(f * 32 + ntf * 16 + col) * 64 + kk * 32 + half * 8);
#pragma unroll
        for (int m = 0; m < 2; ++m)
          acc1[m][ntf] = __builtin_amdgcn_mfma_f32_16x16x32_bf16(
              xa[m][kk], b1, acc1[m][ntf], 0, 0, 0);
      }
#pragma unroll
    for (int m = 0; m < 2; ++m)
#pragma unroll
      for (int ntf = 0; ntf < 2; ++ntf)
#pragma unroll
        for (int reg = 0; reg < 4; ++reg)
          aT[wid][m * 16 + half * 4 + reg][ntf * 16 + col] = tanh_f(acc1[m][ntf][reg]);
    short8 a2[2];
#pragma unroll
    for (int m = 0; m < 2; ++m) {
      const float4 v0 = *reinterpret_cast<const float4*>(&aT[wid][m * 16 + col][half * 8]);
      const float4 v1 = *reinterpret_cast<const float4*>(&aT[wid][m * 16 + col][half * 8 + 4]);
      a2[m] = cvt8(v0, v1);
    }
    f32x4 acc2[2][4];
#pragma unroll
    for (int m = 0; m < 2; ++m)
#pragma unroll
      for (int nt = 0; nt < 4; ++nt) acc2[m][nt] = (f32x4){0.f, 0.f, 0.f, 0.f};
#pragma unroll
    for (int nt = 0; nt < 4; ++nt) {
      const short8 b2 = lds8(w2Tb + (size_t)f * 2048 + (nt * 16 + col) * 32 + half * 8);
#pragma unroll
      for (int m = 0; m < 2; ++m)
        acc2[m][nt] = __builtin_amdgcn_mfma_f32_16x16x32_bf16(
            a2[m], b2, acc2[m][nt], 0, 0, 0);
    }
    float tmf4[4];
#pragma unroll
    for (int nt = 0; nt < 4; ++nt) tmf4[nt] = tmf[nt * 16 + col];
#pragma unroll
    for (int m = 0; m < 2; ++m)
#pragma unroll
      for (int nt = 0; nt < 4; ++nt)
#pragma unroll
        for (int reg = 0; reg < 4; ++reg)
          xT[wid][m * 16 + half * 4 + reg][nt * 16 + col] =
              fmaf(xxv[m][nt][reg], tmf4[nt] + acc2[m][nt][reg], xcv[m][nt][reg]);
  };
  // A-layout 3-product fragments of the stream currently in xT
  auto xT_afrag = [&](short8 ah[2][2], short8 al[2][2]) {
#pragma unroll
    for (int m = 0; m < 2; ++m)
#pragma unroll
      for (int kk = 0; kk < 2; ++kk)
        splitload(&xT[wid][m * 16 + col][kk * 32 + half * 8], ah[m][kk], al[m][kk]);
  };
  // proj GEMM vs pre-converted hi/lo weights (linear [out][in] layout)
  auto proj_gemm = [&](const short* __restrict__ Wh, const short* __restrict__ Wl,
                       const short8 ah[2][2], const short8 al[2][2], f32x4 acc[2][4]) {
#pragma unroll
    for (int m = 0; m < 2; ++m)
#pragma unroll
      for (int n = 0; n < 4; ++n) acc[m][n] = (f32x4){0.f, 0.f, 0.f, 0.f};
#pragma unroll
    for (int n = 0; n < 4; ++n)
#pragma unroll
      for (int kk = 0; kk < 2; ++kk) {
        const short8 bh = lds8(Wh + (size_t)(n * 16 + col) * CC + kk * 32 + half * 8);
        const short8 bl = lds8(Wl + (size_t)(n * 16 + col) * CC + kk * 32 + half * 8);
#pragma unroll
        for (int m = 0; m < 2; ++m)
          acc[m][n] = mfma3(ah[m][kk], al[m][kk], bh, bl, acc[m][n]);
      }
  };

  short8 ah[2][2], al[2][2];

  // ---- phase W: xw -> decay MLP -> ew (held in regs) ----
  mix_f(0, tm_w);
  short8 xwh[2][2];
#pragma unroll
  for (int m = 0; m < 2; ++m)
#pragma unroll
    for (int kk = 0; kk < 2; ++kk) {
      const float4 v0 = *reinterpret_cast<const float4*>(&xT[wid][m * 16 + col][kk * 32 + half * 8]);
      const float4 v1 = *reinterpret_cast<const float4*>(&xT[wid][m * 16 + col][kk * 32 + half * 8 + 4]);
      xwh[m][kk] = cvt8(v0, v1);
    }
  f32x4 hcc[2][4];
#pragma unroll
  for (int m = 0; m < 2; ++m)
#pragma unroll
    for (int nt = 0; nt < 4; ++nt) hcc[m][nt] = (f32x4){0.f, 0.f, 0.f, 0.f};
#pragma unroll
  for (int nt = 0; nt < 4; ++nt)
#pragma unroll
    for (int kk = 0; kk < 2; ++kk) {
      const short8 bd = lds8(d1Tb + (size_t)(nt * 16 + col) * 64 + kk * 32 + half * 8);
#pragma unroll
      for (int m = 0; m < 2; ++m)
        hcc[m][nt] = __builtin_amdgcn_mfma_f32_16x16x32_bf16(
            xwh[m][kk], bd, hcc[m][nt], 0, 0, 0);
    }
#pragma unroll
  for (int m = 0; m < 2; ++m)
#pragma unroll
    for (int nt = 0; nt < 4; ++nt)
#pragma unroll
      for (int reg = 0; reg < 4; ++reg)
        xT[wid][m * 16 + half * 4 + reg][nt * 16 + col] = tanh_f(hcc[m][nt][reg]);
#pragma unroll
  for (int m = 0; m < 2; ++m)
#pragma unroll
    for (int kk = 0; kk < 2; ++kk) {
      const float4 v0 = *reinterpret_cast<const float4*>(&xT[wid][m * 16 + col][kk * 32 + half * 8]);
      const float4 v1 = *reinterpret_cast<const float4*>(&xT[wid][m * 16 + col][kk * 32 + half * 8 + 4]);
      xwh[m][kk] = cvt8(v0, v1);
    }
  f32x4 wfa[2][4];
#pragma unroll
  for (int m = 0; m < 2; ++m)
#pragma unroll
    for (int nt = 0; nt < 4; ++nt) wfa[m][nt] = (f32x4){0.f, 0.f, 0.f, 0.f};
#pragma unroll
  for (int nt = 0; nt < 4; ++nt)
#pragma unroll
    for (int kk = 0; kk < 2; ++kk) {
      const short8 bd = lds8(d2Tb + (size_t)(nt * 16 + col) * 64 + kk * 32 + half * 8);
#pragma unroll
      for (int m = 0; m < 2; ++m)
        wfa[m][nt] = __builtin_amdgcn_mfma_f32_16x16x32_bf16(
            xwh[m][kk], bd, wfa[m][nt], 0, 0, 0);
    }
  float ewv[2][4][4];
  {
    float td4[4];
#pragma unroll
    for (int nt = 0; nt < 4; ++nt) td4[nt] = t_decay[nt * 16 + col];
#pragma unroll
    for (int m = 0; m < 2; ++m)
#pragma unroll
      for (int nt = 0; nt < 4; ++nt)
#pragma unroll
        for (int reg = 0; reg < 4; ++reg)
          ewv[m][nt][reg] = __expf(wfa[m][nt][reg] + td4[nt]);
  }

  // ---- phase R ----
  mix_f(3, tm_r);
  xT_afrag(ah, al);
  f32x4 accr[2][4];
  proj_gemm(Whi, Wlo, ah, al, accr);                    // Wr

  // ---- phase K + ct + full rkdc write ----
  mix_f(1, tm_k);
  xT_afrag(ah, al);
  f32x4 acck[2][4];
  proj_gemm(Whi + 4096, Wlo + 4096, ah, al, acck);      // Wk

  float uv[4];
#pragma unroll
  for (int n = 0; n < 4; ++n) uv[n] = u[n * 16 + col];
#pragma unroll
  for (int m = 0; m < 2; ++m) {
    float ctv[4];
#pragma unroll
    for (int reg = 0; reg < 4; ++reg) {
      float p = 0.f;
#pragma unroll
      for (int n = 0; n < 4; ++n)
        p += accr[m][n][reg] * uv[n] * acck[m][n][reg];
      p += __shfl_xor(p, 1, 64);
      p += __shfl_xor(p, 2, 64);
      p += __shfl_xor(p, 4, 64);
      p += __shfl_xor(p, 8, 64);
      ctv[reg] = p;
    }
#pragma unroll
    for (int n = 0; n < 4; ++n)
#pragma unroll
      for (int reg = 0; reg < 4; ++reg) {
        const int token = tok0 + m * 16 + half * 4 + reg;
        const size_t o = (size_t)token * CC + n * 16 + col;
        *reinterpret_cast<float4*>(rkdc + 4 * o) =
            make_float4(accr[m][n][reg], acck[m][n][reg], ewv[m][n][reg], ctv[reg]);
      }
  }

  // ---- phase V ----
  mix_f(2, tm_v);
  xT_afrag(ah, al);
  proj_gemm(Whi + 2 * 4096, Wlo + 2 * 4096, ah, al, accr);  // Wv
#pragma unroll
  for (int m = 0; m < 2; ++m)
#pragma unroll
    for (int n = 0; n < 4; ++n)
#pragma unroll
      for (int reg = 0; reg < 4; ++reg) {
        const int token = tok0 + m * 16 + half * 4 + reg;
        v_o[(size_t)token * CC + n * 16 + col] = accr[m][n][reg];
      }

  // ---- phase G ----
  mix_f(4, tm_g);
  xT_afrag(ah, al);
  proj_gemm(Whi + 3 * 4096, Wlo + 3 * 4096, ah, al, accr);  // Wg
#pragma unroll
  for (int m = 0; m < 2; ++m)
#pragma unroll
    for (int n = 0; n < 4; ++n)
#pragma unroll
      for (int reg = 0; reg < 4; ++reg) {
        const int token = tok0 + m * 16 + half * 4 + reg;
        const float gg = accr[m][n][reg];
        g_o[(size_t)token * CC + n * 16 + col] = gg / (1.f + __expf(-gg));
      }
}

// ---- A (MFMA): S^T[j][i] = exp(-cumEnd[i]) * sum_s v[s][j] k~[s][i] ------
__global__ __launch_bounds__(128) void chunkA_mfma_kernel(
    const float4* __restrict__ rkdc, const float* __restrict__ v_i,
    float* __restrict__ SlocT, float* __restrict__ Dp)
{
  __shared__ float ktS[2][64 * SW];
  __shared__ float vtS[2][64 * SW];
  __shared__ float cumS[2][64];
  const int lane = threadIdx.x & 63;
  const int w = threadIdx.x >> 6;
  const int bch = __builtin_amdgcn_readfirstlane((blockIdx.x << 1) + w);
  float* ktL = ktS[w];
  float* vtL = vtS[w];
  float* cumL = cumS[w];
  const int col = lane & 15, half = lane >> 4;

  const float4* fq = rkdc + (size_t)bch * (CL * CC) + lane;
  const float* vq = v_i + (size_t)bch * (CL * CC) + lane;

  float cum = 0.f;
  for (int t = 0; t < CL; ++t) {
    const float4 f = fq[t * CC];
    const float vv = vq[t * CC];
    cum += f.z;
    ktL[lane * SW + t] = f.y * __expf(cum);
    vtL[lane * SW + t] = vv;
  }
  cumL[lane] = cum;
  Dp[(size_t)bch * CC + lane] = __expf(-cum);

  short8 vah[4], val[4], kbh[4], kbl[4];
#pragma unroll
  for (int m = 0; m < 4; ++m)
    splitload(vtL + (m * 16 + col) * SW + half * 8, vah[m], val[m]);
#pragma unroll
  for (int n = 0; n < 4; ++n)
    splitload(ktL + (n * 16 + col) * SW + half * 8, kbh[n], kbl[n]);

  f32x4 acc[4][4];
#pragma unroll
  for (int m = 0; m < 4; ++m)
#pragma unroll
    for (int n = 0; n < 4; ++n) {
      acc[m][n] = (f32x4){0.f, 0.f, 0.f, 0.f};
      acc[m][n] = mfma3(vah[m], val[m], kbh[n], kbl[n], acc[m][n]);
    }

  float acl[4];
#pragma unroll
  for (int n = 0; n < 4; ++n) acl[n] = __expf(-cumL[n * 16 + col]);

  float* so = SlocT + (size_t)bch * (CC * CC);
#pragma unroll
  for (int m = 0; m < 4; ++m)
#pragma unroll
    for (int n = 0; n < 4; ++n)
#pragma unroll
      for (int reg = 0; reg < 4; ++reg) {
        const int jj = m * 16 + half * 4 + reg;
        const int ii = n * 16 + col;
        so[jj * CC + ii] = acc[m][n][reg] * acl[n];
      }
}

// ---- B: in-place combine over chunks (transposed [j][i] layout) ----------
__global__ __launch_bounds__(1024) void combine_kernel(
    float* __restrict__ buf, const float* __restrict__ Dp)
{
  const int b = blockIdx.x, tid = threadIdx.x;
  __shared__ float sDp[NCH * CC];
  for (int idx = tid; idx < NCH * CC; idx += 1024)
    sDp[idx] = Dp[(size_t)b * NCH * CC + idx];
  __syncthreads();
  float run[4] = {0.f, 0.f, 0.f, 0.f};
  for (int ch = 0; ch < NCH; ++ch) {
    const size_t base = ((size_t)(b * NCH + ch)) * (CC * CC);
    const float* drow = sDp + ch * CC;
#pragma unroll
    for (int k2 = 0; k2 < 4; ++k2) {
      const int idx = tid + (k2 << 10);
      const float tmp = buf[base + idx];
      buf[base + idx] = run[k2];
      run[k2] = fmaf(run[k2], drow[idx & 63], tmp);
    }
  }
}

// ---- C (MFMA): y = mask(R~K~^T, diag<-ct)@V + R~@S0; GN; *g; @Wo^T -------
__global__ __launch_bounds__(128) void scanC_mfma_kernel(
    const float4* __restrict__ rkdc, const float* __restrict__ v_i,
    const float* __restrict__ S0T, const float* __restrict__ g_i,
    const float* __restrict__ ln_w, const float* __restrict__ ln_b,
    const short* __restrict__ Wohi, const short* __restrict__ Wolo,
    float* __restrict__ out)
{
  __shared__ float rtS[2][32 * SA];
  __shared__ float ktS[2][32 * SA];
  __shared__ float vtS[2][64 * SW];
  __shared__ float ctS[2][CL];
  const int lane = threadIdx.x & 63;
  const int w = threadIdx.x >> 6;
  const int bch = __builtin_amdgcn_readfirstlane((blockIdx.x << 1) + w);
  float* rtL = rtS[w];
  float* ktL = ktS[w];
  float* vtL = vtS[w];
  float* ctL = ctS[w];
  const int col = lane & 15, half = lane >> 4;

  const float4* fq = rkdc + (size_t)bch * (CL * CC) + lane;
  const float* vq = v_i + (size_t)bch * (CL * CC) + lane;

  float cum = 0.f;
  for (int t = 0; t < CL; ++t) {
    const float4 f = fq[t * CC];
    const float vv = vq[t * CC];
    rtL[t * SA + lane] = f.x * __expf(-cum);
    cum += f.z;
    ktL[t * SA + lane] = f.y * __expf(cum);
    vtL[lane * SW + t] = vv;
    if (lane == 0) ctL[t] = f.w;
  }

  short8 rah[2][2], ral[2][2];
#pragma unroll
  for (int m = 0; m < 2; ++m)
#pragma unroll
    for (int kk = 0; kk < 2; ++kk)
      splitload(rtL + (m * 16 + col) * SA + kk * 32 + half * 8, rah[m][kk], ral[m][kk]);
  short8 kbh[2][2], kbl[2][2];
#pragma unroll
  for (int n = 0; n < 2; ++n)
#pragma unroll
    for (int kk = 0; kk < 2; ++kk)
      splitload(ktL + (n * 16 + col) * SA + kk * 32 + half * 8, kbh[n][kk], kbl[n][kk]);

  f32x4 pacc[2][2];
#pragma unroll
  for (int m = 0; m < 2; ++m)
#pragma unroll
    for (int n = 0; n < 2; ++n) {
      pacc[m][n] = (f32x4){0.f, 0.f, 0.f, 0.f};
#pragma unroll
      for (int kk = 0; kk < 2; ++kk)
        pacc[m][n] = mfma3(rah[m][kk], ral[m][kk], kbh[n][kk], kbl[n][kk], pacc[m][n]);
    }

#pragma unroll
  for (int m = 0; m < 2; ++m)
#pragma unroll
    for (int n = 0; n < 2; ++n)
#pragma unroll
      for (int reg = 0; reg < 4; ++reg) {
        const int tt = m * 16 + half * 4 + reg;
        const int ss = n * 16 + col;
        const float pv = (ss < tt) ? pacc[m][n][reg] : (ss == tt ? ctL[tt] : 0.f);
        ktL[tt * SA + ss] = pv;
      }

  short8 pah[2], pal[2];
#pragma unroll
  for (int m = 0; m < 2; ++m)
    splitload(ktL + (m * 16 + col) * SA + half * 8, pah[m], pal[m]);
  short8 vbh[4], vbl[4];
#pragma unroll
  for (int n = 0; n < 4; ++n)
    splitload(vtL + (n * 16 + col) * SW + half * 8, vbh[n], vbl[n]);

  f32x4 yacc[2][4];
#pragma unroll
  for (int m = 0; m < 2; ++m)
#pragma unroll
    for (int n = 0; n < 4; ++n) {
      yacc[m][n] = (f32x4){0.f, 0.f, 0.f, 0.f};
      yacc[m][n] = mfma3(pah[m], pal[m], vbh[n], vbl[n], yacc[m][n]);
    }

  const float* s0b = S0T + (size_t)bch * (CC * CC);
#pragma unroll
  for (int kk = 0; kk < 2; ++kk) {
    short8 sbh[4], sbl[4];
#pragma unroll
    for (int n = 0; n < 4; ++n)
      splitload(s0b + (size_t)(n * 16 + col) * CC + kk * 32 + half * 8, sbh[n], sbl[n]);
#pragma unroll
    for (int m = 0; m < 2; ++m)
#pragma unroll
      for (int n = 0; n < 4; ++n)
        yacc[m][n] = mfma3(rah[m][kk], ral[m][kk], sbh[n], sbl[n], yacc[m][n]);
  }

  float s1v[2][4], s2v[2][4];
#pragma unroll
  for (int m = 0; m < 2; ++m)
#pragma unroll
    for (int reg = 0; reg < 4; ++reg) {
      float a = 0.f, b2 = 0.f;
#pragma unroll
      for (int n = 0; n < 4; ++n) {
        const float y = yacc[m][n][reg];
        a += y; b2 += y * y;
      }
      a += __shfl_xor(a, 1, 64); b2 += __shfl_xor(b2, 1, 64);
      a += __shfl_xor(a, 2, 64); b2 += __shfl_xor(b2, 2, 64);
      a += __shfl_xor(a, 4, 64); b2 += __shfl_xor(b2, 4, 64);
      a += __shfl_xor(a, 8, 64); b2 += __shfl_xor(b2, 8, 64);
      s1v[m][reg] = a; s2v[m][reg] = b2;
    }

#pragma unroll
  for (int m = 0; m < 2; ++m)
#pragma unroll
    for (int n = 0; n < 4; ++n) {
      const int cj = n * 16 + col;
      const float lnw = ln_w[cj], lnb = ln_b[cj];
#pragma unroll
      for (int reg = 0; reg < 4; ++reg) {
        const int tt = m * 16 + half * 4 + reg;
        const float y = yacc[m][n][reg];
        const float mu = s1v[m][reg] * (1.f / CC);
        const float var = s2v[m][reg] * (1.f / CC) - mu * mu;
        const float z = (y - mu) * rsqrtf(var + GN_EPS) * lnw + lnb;
        const float gg = g_i[((size_t)bch * CL + tt) * CC + cj];
        rtL[tt * SA + cj] = z * gg;
      }
    }

  f32x4 oacc[2][4];
#pragma unroll
  for (int m = 0; m < 2; ++m)
#pragma unroll
    for (int n = 0; n < 4; ++n) oacc[m][n] = (f32x4){0.f, 0.f, 0.f, 0.f};
#pragma unroll
  for (int kk = 0; kk < 2; ++kk) {
    short8 zah[2], zal[2];
#pragma unroll
    for (int m = 0; m < 2; ++m)
      splitload(rtL + (m * 16 + col) * SA + kk * 32 + half * 8, zah[m], zal[m]);
#pragma unroll
    for (int n = 0; n < 4; ++n) {
      const short8 wbh = lds8(Wohi + (size_t)(n * 16 + col) * CC + kk * 32 + half * 8);
      const short8 wbl = lds8(Wolo + (size_t)(n * 16 + col) * CC + kk * 32 + half * 8);
#pragma unroll
      for (int m = 0; m < 2; ++m)
        oacc[m][n] = mfma3(zah[m], zal[m], wbh, wbl, oacc[m][n]);
    }
  }

#pragma unroll
  for (int m = 0; m < 2; ++m)
#pragma unroll
    for (int n = 0; n < 4; ++n)
#pragma unroll
      for (int reg = 0; reg < 4; ++reg) {
        const int tt = m * 16 + half * 4 + reg;
        out[((size_t)bch * CL + tt) * CC + n * 16 + col] = oacc[m][n][reg];
      }
}

extern "C" void kernel_launch(void* const* d_in, const int* in_sizes, int n_in,
                              void* d_out, int out_size, void* d_ws, size_t ws_size,
                              hipStream_t stream) {
  const float* x       = (const float*)d_in[0];
  const float* tm_x    = (const float*)d_in[1];
  const float* tm_w    = (const float*)d_in[2];
  const float* tm_k    = (const float*)d_in[3];
  const float* tm_v    = (const float*)d_in[4];
  const float* tm_r    = (const float*)d_in[5];
  const float* tm_g    = (const float*)d_in[6];
  const float* maa_w1  = (const float*)d_in[7];
  const float* maa_w2  = (const float*)d_in[8];
  const float* t_decay = (const float*)d_in[9];
  const float* dec_w1  = (const float*)d_in[10];
  const float* dec_w2  = (const float*)d_in[11];
  const float* u       = (const float*)d_in[12];
  const float* Wr      = (const float*)d_in[13];
  const float* Wk      = (const float*)d_in[14];
  const float* Wv      = (const float*)d_in[15];
  const float* Wg      = (const float*)d_in[16];
  const float* Wo      = (const float*)d_in[17];
  const float* ln_w    = (const float*)d_in[18];
  const float* ln_b    = (const float*)d_in[19];

  const size_t M = (size_t)BT * CC;  // 4.19M floats
  float* ws   = (float*)d_ws;
  float* scb  = ws;                  // SlocT==S0T (in-place), 2M floats
  float* Dp   = ws + 2 * M;
  float* g_o  = ws + 4 * M;
  float* v_o  = ws + 5 * M;
  float* rkdc = ws + 6 * M;
  short* w1Tb = (short*)(ws + 10 * M);
  short* w2Tb = w1Tb + 10240;
  short* d1Tb = w2Tb + 10240;
  short* d2Tb = d1Tb + 4096;
  short* Whi  = d2Tb + 4096;
  short* Wlo  = Whi + 5 * 4096;
  float* out  = (float*)d_out;

  preT_kernel<<<64, 256, 0, stream>>>(
      maa_w1, maa_w2, dec_w1, dec_w2, Wr, Wk, Wv, Wg, Wo,
      w1Tb, w2Tb, d1Tb, d2Tb, Whi, Wlo);

  prep_fused_kernel<<<BT / 128, 256, 0, stream>>>(
      x, tm_x, tm_w, tm_k, tm_v, tm_r, tm_g,
      w1Tb, w2Tb, d1Tb, d2Tb, t_decay, u,
      Whi, Wlo, rkdc, v_o, g_o);

  chunkA_mfma_kernel<<<(BB * NCH) / 2, 128, 0, stream>>>(
      (const float4*)rkdc, v_o, scb, Dp);

  combine_kernel<<<BB, 1024, 0, stream>>>(scb, Dp);

  scanC_mfma_kernel<<<(BB * NCH) / 2, 128, 0, stream>>>(
      (const float4*)rkdc, v_o, scb, g_o, ln_w, ln_b,
      Whi + 4 * 4096, Wlo + 4 * 4096, out);
}